// Round 5
// baseline (104.836 us; speedup 1.0000x reference)
//
#include <hip/hip_runtime.h>

// LocBlock2dNT: x (64,64,64,64) f32, w (256,64,16,16,16) f32
// out (64,256,16,16) f32 = relu( einsum('ncpqf,ocpqf->nopq', patches, w) / 32 )
//
// Pass 1 (prep): unfold+convert x -> xT bf16, layout [pq][c][koct2][n64][k8]
//   (each (pq,c,koct) = 1 KB contiguous). Coalesced read & write.
// Pass 2 (gemm): block = (p, q-pair, o-half). A staged as 1-KB runs (bf16),
//   w staged as 128-B runs (f32), 3-deep global_load_lds, counted vmcnt(10).
//   Output relu-scaled -> ws2 [pq][o][n] (16-B contiguous stores).
// Pass 3 (post): transpose ws2 -> out [n][o][pq] (coalesced).

typedef short bf16x8 __attribute__((ext_vector_type(8)));
typedef short bf16x4 __attribute__((ext_vector_type(4)));
typedef float f32x4  __attribute__((ext_vector_type(4)));

__device__ __forceinline__ short f2bf(float f) {
    union { float f; unsigned u; } v; v.f = f;
    return (short)((v.u + 0x7FFFu + ((v.u >> 16) & 1u)) >> 16);   // RNE
}

__device__ __forceinline__ bf16x8 pack8(f32x4 a, f32x4 b) {
    bf16x8 r;
    r[0] = f2bf(a[0]); r[1] = f2bf(a[1]); r[2] = f2bf(a[2]); r[3] = f2bf(a[3]);
    r[4] = f2bf(b[0]); r[5] = f2bf(b[1]); r[6] = f2bf(b[2]); r[7] = f2bf(b[3]);
    return r;
}

__device__ __forceinline__ void gload16(const void* g, void* l) {
    __builtin_amdgcn_global_load_lds(
        (const __attribute__((address_space(1))) void*)g,
        (__attribute__((address_space(3))) void*)l, 16, 0, 0);
}

// ---------------------------------------------------------------- pass 1
// block = (p, c). Reads x[:, c, 4p..4p+4, :] (256-B runs), writes
// xT[p*16+q][c][koct][n][k8] (1-KB runs). LDS tile padded pitch 2056 B.
__global__ __launch_bounds__(256)
void prep_unfold(const float* __restrict__ x, short* __restrict__ xT) {
    __shared__ __align__(16) char tile[16 * 2056];   // [q] pitch 2056
    const int bid = blockIdx.x;
    const int p = bid >> 6, c = bid & 63;
    const int t = (int)threadIdx.x;

#pragma unroll
    for (int it = 0; it < 16; ++it) {
        const int id = it * 256 + t;                 // 4096 chunks of 16 B
        const int n = id >> 6, fr = (id >> 4) & 3, cq = id & 15;
        const f32x4 v = *(const f32x4*)(x + (size_t)n * 262144u
                                          + (size_t)c * 4096u
                                          + (size_t)(4 * p + fr) * 64u
                                          + (size_t)(cq * 4));
        // q = cq, koct = fr>>1, k8 = (fr&1)*4 + j
        bf16x4 b; b[0] = f2bf(v[0]); b[1] = f2bf(v[1]);
                  b[2] = f2bf(v[2]); b[3] = f2bf(v[3]);
        *(bf16x4*)(tile + cq * 2056 + (fr >> 1) * 1024 + n * 16
                        + (fr & 1) * 8) = b;
    }
    __syncthreads();

#pragma unroll
    for (int it = 0; it < 8; ++it) {
        const int id = it * 256 + t;                 // 2048 chunks of 16 B
        const int q = id >> 7, s = id & 127;
        const int koct = s >> 6, n = s & 63;
        const bf16x8 v = *(const bf16x8*)(tile + q * 2056 + koct * 1024 + n * 16);
        *(bf16x8*)(xT + (size_t)(p * 16 + q) * 65536u + (size_t)c * 1024u
                      + (size_t)koct * 512u + (size_t)n * 8u) = v;
    }
}

// ---------------------------------------------------------------- pass 2
__global__ __launch_bounds__(512)
void locblock_gemm(const short* __restrict__ xT, const float* __restrict__ w,
                   float* __restrict__ ws2) {
    // per stage: A 8 chunks x 1088 B = 8704 | B 32 KB  -> 41472 B; x3 = 124.4 KB
    __shared__ __align__(16) char smem[3][41472];

    const int hw = blockIdx.x;
    const int lb = (hw & 7) * 32 + (hw >> 3);        // bijective, 256 % 8 == 0
    const int p  = lb >> 4;
    const int q2 = (lb >> 1) & 7;                    // q = 2*q2 + qw
    const int oh = lb & 1;                           // o half

    const int tid  = (int)threadIdx.x;
    const int lane = tid & 63;
    const int wv   = tid >> 6;                       // 0..7
    const int l15  = lane & 15;
    const int kq   = lane >> 4;                      // 0..3
    const int qw   = wv & 1;                         // compute: wave's q
    const int nc   = wv >> 1;                        // compute: o-quarter

    // ---- A staging: wave wv loads chunk wv = (qin, c_off, koct) ----
    const int qin  = wv >> 2, acf = (wv >> 1) & 1, akoct = wv & 1;
    const short* asrc = xT + (size_t)(p * 16 + q2 * 2 + qin) * 65536u
                           + (size_t)acf * 1024u + (size_t)akoct * 512u
                           + (size_t)lane * 8u;      // +2048 elems per step

    // ---- B staging: 2048 chunks of 16 B, 4/thread, XOR ^(ol&15) on source ----
    const float* wsrc[4];
#pragma unroll
    for (int j = 0; j < 4; ++j) {
        const int id = j * 512 + tid;
        const int ol = id >> 4, s = id & 15;
        const int u = s ^ (ol & 15);                 // u = c_off*8 + h8
        wsrc[j] = w + (size_t)(oh * 128 + ol) * 262144u + (size_t)(u >> 3) * 4096u
                    + (size_t)p * 256u + (size_t)(q2 * 32) + (size_t)((u & 7) * 4);
    }

    // ---- fragment LDS byte offsets ----
    int aoff[4], boff[2][2];
#pragma unroll
    for (int mf = 0; mf < 4; ++mf)
        aoff[mf] = (qw * 4 + kq) * 1088 + (mf * 16 + l15) * 16;
    {
        const int u1 = (kq >> 1) * 8 + qw * 4 + (kq & 1) * 2;
#pragma unroll
        for (int nf = 0; nf < 2; ++nf) {
            const int ol = nc * 32 + nf * 16 + l15;
            boff[nf][0] = 8704 + ol * 256 + ((u1       ^ l15) * 16);
            boff[nf][1] = 8704 + ol * 256 + (((u1 + 1) ^ l15) * 16);
        }
    }

    f32x4 acc[4][2];
#pragma unroll
    for (int mf = 0; mf < 4; ++mf)
#pragma unroll
        for (int nf = 0; nf < 2; ++nf)
            acc[mf][nf] = (f32x4){0.f, 0.f, 0.f, 0.f};

    auto stage = [&](int t, int buf) {
        char* base = smem[buf];
        gload16(asrc + (size_t)t * 2048u, base + wv * 1088);       // A: 1 load
#pragma unroll
        for (int j = 0; j < 4; ++j)                                 // B: 4 loads
            gload16(wsrc[j] + (size_t)t * 8192u,
                    base + 8704 + j * 8192 + wv * 1024);
    };

    auto compute = [&](int buf) {
        const char* Lb = smem[buf];
        bf16x8 av[4], bv[2];
#pragma unroll
        for (int mf = 0; mf < 4; ++mf)
            av[mf] = *(const bf16x8*)(Lb + aoff[mf]);               // direct bf16
#pragma unroll
        for (int nf = 0; nf < 2; ++nf)
            bv[nf] = pack8(*(const f32x4*)(Lb + boff[nf][0]),
                           *(const f32x4*)(Lb + boff[nf][1]));
#pragma unroll
        for (int mf = 0; mf < 4; ++mf)
#pragma unroll
            for (int nf = 0; nf < 2; ++nf)
                acc[mf][nf] = __builtin_amdgcn_mfma_f32_16x16x32_bf16(
                    av[mf], bv[nf], acc[mf][nf], 0, 0, 0);
    };

    // ---- 3-deep pipeline over 32 K-steps (5 loads/thread per stage) ----
    stage(0, 0);
    stage(1, 1);
    stage(2, 2);
#pragma unroll 1
    for (int t = 0; t < 29; ++t) {
        const int buf = t % 3;
        asm volatile("s_waitcnt vmcnt(10)" ::: "memory");  // stage t landed
        __builtin_amdgcn_s_barrier();
        compute(buf);
        asm volatile("s_waitcnt lgkmcnt(0)" ::: "memory"); // reads retired
        __builtin_amdgcn_s_barrier();
        stage(t + 3, buf);
    }
    asm volatile("s_waitcnt vmcnt(10)" ::: "memory");
    __builtin_amdgcn_s_barrier();
    compute(2);                                            // t = 29
    asm volatile("s_waitcnt vmcnt(5)" ::: "memory");
    __builtin_amdgcn_s_barrier();
    compute(0);                                            // t = 30
    asm volatile("s_waitcnt vmcnt(0)" ::: "memory");
    __builtin_amdgcn_s_barrier();
    compute(1);                                            // t = 31

    // ---- epilogue: relu-scale, store to ws2[pq][o][n] (16-B contiguous) ----
    const float scale = 0.03125f;                    // 1/sqrt(16*64)
    const int pq = p * 16 + q2 * 2 + qw;
#pragma unroll
    for (int mf = 0; mf < 4; ++mf)
#pragma unroll
        for (int nf = 0; nf < 2; ++nf) {
            const int o  = oh * 128 + nc * 32 + nf * 16 + l15;
            const int n0 = mf * 16 + kq * 4;         // C/D row = kq*4 + j
            f32x4 r;
#pragma unroll
            for (int j = 0; j < 4; ++j)
                r[j] = fmaxf(acc[mf][nf][j] * scale, 0.0f);
            *(f32x4*)(ws2 + (size_t)pq * 16384u + (size_t)o * 64u + n0) = r;
        }
}

// ---------------------------------------------------------------- pass 3
__global__ __launch_bounds__(256)
void finish_transpose(const float* __restrict__ ws2, float* __restrict__ out) {
    __shared__ float tile[256 * 68];
    const int o = blockIdx.x;
    const int t = (int)threadIdx.x;

#pragma unroll
    for (int it = 0; it < 16; ++it) {
        const int chunk = it * 256 + t;
        const int pq = chunk >> 4, ng = chunk & 15;
        const f32x4 v = *(const f32x4*)(ws2 + (size_t)pq * 16384u
                                            + (size_t)o * 64u + ng * 4);
        *(f32x4*)&tile[pq * 68 + ng * 4] = v;
    }
    __syncthreads();

    const int n = t >> 2, pqq = t & 3;
#pragma unroll
    for (int i = 0; i < 16; ++i) {
        const int pq0 = i * 16 + pqq * 4;
        f32x4 r;
#pragma unroll
        for (int k = 0; k < 4; ++k)
            r[k] = tile[(pq0 + k) * 68 + n];
        *(f32x4*)(out + (size_t)n * 65536u + (size_t)o * 256u + pq0) = r;
    }
}

extern "C" void kernel_launch(void* const* d_in, const int* in_sizes, int n_in,
                              void* d_out, int out_size, void* d_ws, size_t ws_size,
                              hipStream_t stream) {
    const float* x = (const float*)d_in[0];
    const float* w = (const float*)d_in[1];
    float* out = (float*)d_out;
    short* xT  = (short*)d_ws;                              // 32 MB bf16
    float* ws2 = (float*)((char*)d_ws + (33554432));        // 16 MB f32
    prep_unfold     <<<dim3(1024), dim3(256), 0, stream>>>(x, xT);
    locblock_gemm   <<<dim3(256),  dim3(512), 0, stream>>>(xT, w, ws2);
    finish_transpose<<<dim3(256),  dim3(256), 0, stream>>>(ws2, out);
}

// Round 6
// 104.360 us; speedup vs baseline: 1.0046x; 1.0046x over previous
//
#include <hip/hip_runtime.h>

// LocBlock2dNT: x (64,64,64,64) f32, w (256,64,16,16,16) f32
// out (64,256,16,16) f32 = relu( einsum('ncpqf,ocpqf->nopq', patches, w) / 32 )
//
// Pass 1 (prep): unfold+convert x -> xT bf16, [pq][c][koct][n64][k8]
//   -> A-fragments become lane-contiguous 16-B loads.
// Pass 2 (gemm): block = (p, q-pair, o-half), grid 256 (1/CU).
//   A: direct global->VGPR in fragment layout (no LDS).
//   B (w, streaming-miss): reg-staged 2 steps ahead (breaks the ~10KB/CU
//   global_load_lds DMA in-flight cap), ds_write XOR-swizzled, 2 LDS bufs,
//   one barrier per K-step. relu-scaled -> ws2 [pq][o][n].
// Pass 3 (post): transpose ws2 -> out [n][o][pq] (coalesced).

typedef short bf16x8 __attribute__((ext_vector_type(8)));
typedef short bf16x4 __attribute__((ext_vector_type(4)));
typedef float f32x4  __attribute__((ext_vector_type(4)));

__device__ __forceinline__ short f2bf(float f) {
    union { float f; unsigned u; } v; v.f = f;
    return (short)((v.u + 0x7FFFu + ((v.u >> 16) & 1u)) >> 16);   // RNE
}

__device__ __forceinline__ bf16x8 pack8(f32x4 a, f32x4 b) {
    bf16x8 r;
    r[0] = f2bf(a[0]); r[1] = f2bf(a[1]); r[2] = f2bf(a[2]); r[3] = f2bf(a[3]);
    r[4] = f2bf(b[0]); r[5] = f2bf(b[1]); r[6] = f2bf(b[2]); r[7] = f2bf(b[3]);
    return r;
}

// ---------------------------------------------------------------- pass 1
__global__ __launch_bounds__(256)
void prep_unfold(const float* __restrict__ x, short* __restrict__ xT) {
    __shared__ __align__(16) char tile[16 * 2056];
    const int bid = blockIdx.x;
    const int p = bid >> 6, c = bid & 63;
    const int t = (int)threadIdx.x;

#pragma unroll
    for (int it = 0; it < 16; ++it) {
        const int id = it * 256 + t;
        const int n = id >> 6, fr = (id >> 4) & 3, cq = id & 15;
        const f32x4 v = *(const f32x4*)(x + (size_t)n * 262144u
                                          + (size_t)c * 4096u
                                          + (size_t)(4 * p + fr) * 64u
                                          + (size_t)(cq * 4));
        bf16x4 b; b[0] = f2bf(v[0]); b[1] = f2bf(v[1]);
                  b[2] = f2bf(v[2]); b[3] = f2bf(v[3]);
        *(bf16x4*)(tile + cq * 2056 + (fr >> 1) * 1024 + n * 16
                        + (fr & 1) * 8) = b;
    }
    __syncthreads();

#pragma unroll
    for (int it = 0; it < 8; ++it) {
        const int id = it * 256 + t;
        const int q = id >> 7, s = id & 127;
        const int koct = s >> 6, n = s & 63;
        const bf16x8 v = *(const bf16x8*)(tile + q * 2056 + koct * 1024 + n * 16);
        *(bf16x8*)(xT + (size_t)(p * 16 + q) * 65536u + (size_t)c * 1024u
                      + (size_t)koct * 512u + (size_t)n * 8u) = v;
    }
}

// ---------------------------------------------------------------- pass 2
__global__ __launch_bounds__(512)
void locblock_gemm(const short* __restrict__ xT, const float* __restrict__ w,
                   float* __restrict__ ws2) {
    __shared__ __align__(16) char smem[2][32768];    // 2 x B-tile (32 KB)

    const int hw = blockIdx.x;
    const int lb = (hw & 7) * 32 + (hw >> 3);        // XCD swizzle, bijective
    const int p  = lb >> 4;
    const int q2 = (lb >> 1) & 7;                    // q = 2*q2 + qw
    const int oh = lb & 1;

    const int tid  = (int)threadIdx.x;
    const int lane = tid & 63;
    const int wv   = tid >> 6;
    const int l15  = lane & 15;
    const int kq   = lane >> 4;
    const int qw   = wv & 1;
    const int nc   = wv >> 1;

    // ---- A: direct fragment loads from xT (advance 2048 shorts / step) ----
    const short* asrc = xT + (size_t)(p * 16 + q2 * 2 + qw) * 65536u
                           + (size_t)(kq >> 1) * 1024u + (size_t)(kq & 1) * 512u
                           + (size_t)l15 * 8u;

    // ---- B global sources: id = j*512+tid -> (ol, u); natural (no XOR) ----
    const float* bsrc[4];
#pragma unroll
    for (int j = 0; j < 4; ++j) {
        const int id = j * 512 + tid;
        const int ol = id >> 4, u = id & 15;
        bsrc[j] = w + (size_t)(oh * 128 + ol) * 262144u + (size_t)(u >> 3) * 4096u
                    + (size_t)p * 256u + (size_t)(q2 * 32) + (size_t)((u & 7) * 4);
    }
    // ---- B ds_write offsets (floats): phys slot = u ^ (ol&15) ----
    int wofs[4];
#pragma unroll
    for (int j = 0; j < 4; ++j) {
        const int id = j * 512 + tid;
        const int ol = id >> 4;
        wofs[j] = ol * 64 + (((tid & 15) ^ (ol & 15)) * 4);
    }
    // ---- B ds_read offsets (bytes) ----
    const int u1 = (kq >> 1) * 8 + qw * 4 + (kq & 1) * 2;
    int boff[2][2];
#pragma unroll
    for (int nf = 0; nf < 2; ++nf) {
        const int ol = nc * 32 + nf * 16 + l15;
        boff[nf][0] = ol * 256 + (((u1)     ^ l15) * 16);
        boff[nf][1] = ol * 256 + (((u1 + 1) ^ l15) * 16);
    }

    f32x4 acc[4][2];
#pragma unroll
    for (int mf = 0; mf < 4; ++mf)
#pragma unroll
        for (int nf = 0; nf < 2; ++nf)
            acc[mf][nf] = (f32x4){0.f, 0.f, 0.f, 0.f};

    bf16x8 as0[4], as1[4];                           // A reg sets (even/odd)
    f32x4  bs0[4], bs1[4];                           // B reg sets

#define ISSUE_A(AS, T)                                                        \
    _Pragma("unroll") for (int mf = 0; mf < 4; ++mf)                          \
        AS[mf] = *(const bf16x8*)(asrc + (size_t)(T) * 2048u + mf * 128);
#define ISSUE_B(BS, T)                                                        \
    _Pragma("unroll") for (int j = 0; j < 4; ++j)                             \
        BS[j] = *(const f32x4*)(bsrc[j] + (size_t)(T) * 8192u);
#define DSWRITE(BS, BUF)                                                      \
    { float* Wb = (float*)(smem[BUF]);                                        \
      _Pragma("unroll") for (int j = 0; j < 4; ++j)                           \
          *(f32x4*)(Wb + wofs[j]) = BS[j]; }
#define COMPUTE(AS, BUF)                                                      \
    { const char* Lb = smem[BUF];                                             \
      bf16x8 bv0 = pack8(*(const f32x4*)(Lb + boff[0][0]),                    \
                         *(const f32x4*)(Lb + boff[0][1]));                   \
      bf16x8 bv1 = pack8(*(const f32x4*)(Lb + boff[1][0]),                    \
                         *(const f32x4*)(Lb + boff[1][1]));                   \
      _Pragma("unroll") for (int mf = 0; mf < 4; ++mf) {                      \
          acc[mf][0] = __builtin_amdgcn_mfma_f32_16x16x32_bf16(               \
              AS[mf], bv0, acc[mf][0], 0, 0, 0);                              \
          acc[mf][1] = __builtin_amdgcn_mfma_f32_16x16x32_bf16(               \
              AS[mf], bv1, acc[mf][1], 0, 0, 0);                              \
      } }

    // ---- prologue ----
    ISSUE_A(as0, 0); ISSUE_A(as1, 1);
    ISSUE_B(bs0, 0); ISSUE_B(bs1, 1);
    asm volatile("s_waitcnt vmcnt(0)" ::: "memory");
    DSWRITE(bs0, 0);
    asm volatile("s_waitcnt lgkmcnt(0)" ::: "memory");
    __builtin_amdgcn_s_barrier();

    // ---- main loop: t = 0..29, two steps per iteration ----
#pragma unroll 1
    for (int t = 0; t < 30; t += 2) {
        // even step t: read buf0/as0; issue t+2 -> as0/bs0; write stage t+1
        COMPUTE(as0, 0);
        ISSUE_A(as0, t + 2);
        ISSUE_B(bs0, t + 2);
        asm volatile("s_waitcnt vmcnt(8)" ::: "memory");   // B(t+1) landed
        DSWRITE(bs1, 1);
        asm volatile("s_waitcnt lgkmcnt(0)" ::: "memory");
        __builtin_amdgcn_s_barrier();
        // odd step t+1
        COMPUTE(as1, 1);
        ISSUE_A(as1, t + 3);
        ISSUE_B(bs1, t + 3);
        asm volatile("s_waitcnt vmcnt(8)" ::: "memory");   // B(t+2) landed
        DSWRITE(bs0, 0);
        asm volatile("s_waitcnt lgkmcnt(0)" ::: "memory");
        __builtin_amdgcn_s_barrier();
    }
    // ---- tail: t = 30, 31 (A/B 30,31 already in regs; 30 already written) ----
    COMPUTE(as0, 0);                                       // t = 30
    asm volatile("s_waitcnt vmcnt(0)" ::: "memory");       // B(31) landed
    DSWRITE(bs1, 1);
    asm volatile("s_waitcnt lgkmcnt(0)" ::: "memory");
    __builtin_amdgcn_s_barrier();
    COMPUTE(as1, 1);                                       // t = 31

#undef ISSUE_A
#undef ISSUE_B
#undef DSWRITE
#undef COMPUTE

    // ---- epilogue: relu-scale -> ws2[pq][o][n] (64-B runs per wave) ----
    const float scale = 0.03125f;
    const int pq = p * 16 + q2 * 2 + qw;
#pragma unroll
    for (int mf = 0; mf < 4; ++mf)
#pragma unroll
        for (int nf = 0; nf < 2; ++nf) {
            const int o  = oh * 128 + nc * 32 + nf * 16 + l15;
            const int n0 = mf * 16 + kq * 4;
            f32x4 r;
#pragma unroll
            for (int j = 0; j < 4; ++j)
                r[j] = fmaxf(acc[mf][nf][j] * scale, 0.0f);
            *(f32x4*)(ws2 + (size_t)pq * 16384u + (size_t)o * 64u + n0) = r;
        }
}

// ---------------------------------------------------------------- pass 3
__global__ __launch_bounds__(256)
void finish_transpose(const float* __restrict__ ws2, float* __restrict__ out) {
    __shared__ float tile[256 * 68];
    const int o = blockIdx.x;
    const int t = (int)threadIdx.x;

#pragma unroll
    for (int it = 0; it < 16; ++it) {
        const int chunk = it * 256 + t;
        const int pq = chunk >> 4, ng = chunk & 15;
        const f32x4 v = *(const f32x4*)(ws2 + (size_t)pq * 16384u
                                            + (size_t)o * 64u + ng * 4);
        *(f32x4*)&tile[pq * 68 + ng * 4] = v;
    }
    __syncthreads();

    const int n = t >> 2, pqq = t & 3;
#pragma unroll
    for (int i = 0; i < 16; ++i) {
        const int pq0 = i * 16 + pqq * 4;
        f32x4 r;
#pragma unroll
        for (int k = 0; k < 4; ++k)
            r[k] = tile[(pq0 + k) * 68 + n];
        *(f32x4*)(out + (size_t)n * 65536u + (size_t)o * 256u + pq0) = r;
    }
}

extern "C" void kernel_launch(void* const* d_in, const int* in_sizes, int n_in,
                              void* d_out, int out_size, void* d_ws, size_t ws_size,
                              hipStream_t stream) {
    const float* x = (const float*)d_in[0];
    const float* w = (const float*)d_in[1];
    float* out = (float*)d_out;
    short* xT  = (short*)d_ws;                              // 32 MB bf16
    float* ws2 = (float*)((char*)d_ws + (33554432));        // 16 MB f32
    prep_unfold     <<<dim3(1024), dim3(256), 0, stream>>>(x, xT);
    locblock_gemm   <<<dim3(256),  dim3(512), 0, stream>>>(xT, w, ws2);
    finish_transpose<<<dim3(256),  dim3(256), 0, stream>>>(ws2, out);
}